// Round 1
// baseline (1799.723 us; speedup 1.0000x reference)
//
#include <hip/hip_runtime.h>
#include <math.h>

#define NG 100000
#define ND 50000
#define EGG 1600000
#define EDG 800000
#define HID 128
#define NH 8

// ---------------- workspace layout (float offsets) ----------------
#define OFF_OUT_GG 0UL          // 12,800,000  (zero-init)
#define OFF_OUT_DG 12800000UL   // 12,800,000  (zero-init)
#define OFF_S_GG   25600000UL   //    800,000  (zero-init)
#define OFF_S_DG   26400000UL   //    800,000  (zero-init)
#define OFF_KPART  27200000UL   //        256  (zero-init)
#define ZERO_CNT   27200256UL
#define OFF_M_GG   27200256UL   //    800,000  (-inf init)
#define OFF_M_DG   28000256UL   //    800,000  (-inf init)
#define NINF_END   28800256UL
#define OFF_XG     28800256UL   // 12,800,000
#define OFF_XD     41600256UL   //  6,400,000
#define OFF_ASG    48000256UL   //    800,000  a_src_gg [NG,8]
#define OFF_ADG    48800256UL   //    800,000  a_dst_gg [NG,8]
#define OFF_ADD    49600256UL   //    800,000  a_dst_dg [NG,8]
#define OFF_ASD    50400256UL   //    400,000  a_src_dg [ND,8]
#define OFF_ATTN   50800256UL   //          2

__device__ __forceinline__ void atomicMaxF(float* addr, float val) {
    if (val >= 0.f) atomicMax((int*)addr, __float_as_int(val));
    else            atomicMin((unsigned int*)addr, __float_as_uint(val));
}

// ---------------- init ----------------
__global__ void init_ws_k(float4* __restrict__ ws) {
    int i = blockIdx.x * 256 + threadIdx.x;
    const int zero4 = (int)(ZERO_CNT / 4);
    const int ninf4 = (int)(NINF_END / 4);
    if (i < zero4) {
        ws[i] = make_float4(0.f, 0.f, 0.f, 0.f);
    } else if (i < ninf4) {
        float n = -INFINITY;
        ws[i] = make_float4(n, n, n, n);
    }
}

// ---------------- projection GEMM: out[n,j] = b[j] + sum_i x[n,i]*W[j,i] ----------------
__launch_bounds__(256)
__global__ void proj_gemm(const float* __restrict__ x, const float* __restrict__ W,
                          const float* __restrict__ bias, float* __restrict__ out, int N) {
    __shared__ float Ws[128 * 132];     // Ws[i*132 + j] = W[j*128 + i]
    __shared__ float rows[8][128];
    for (int idx = threadIdx.x; idx < 128 * 128; idx += 256) {
        int i = idx >> 7, j = idx & 127;
        Ws[i * 132 + j] = W[j * 128 + i];
    }
    __syncthreads();
    int g = threadIdx.x >> 5;   // node subgroup 0..7
    int l = threadIdx.x & 31;   // 32 lanes, 4 cols each
    float4 bvec = *(const float4*)&bias[l * 4];
    for (int base = blockIdx.x * 8; base < N; base += gridDim.x * 8) {
        int n = base + g;
        if (n < N) {
            float4 v = *(const float4*)&x[(size_t)n * 128 + l * 4];
            *(float4*)&rows[g][l * 4] = v;
        }
        __syncthreads();
        if (n < N) {
            float4 acc = bvec;
            #pragma unroll 8
            for (int i = 0; i < 128; i++) {
                float r = rows[g][i];
                float4 w = *(const float4*)&Ws[i * 132 + l * 4];
                acc.x += r * w.x; acc.y += r * w.y; acc.z += r * w.z; acc.w += r * w.w;
            }
            *(float4*)&out[(size_t)n * 128 + l * 4] = acc;
        }
        __syncthreads();
    }
}

// ---------------- per-node attention logit halves ----------------
__launch_bounds__(256)
__global__ void att_scores_gene(const float* __restrict__ xg,
                                const float* __restrict__ w0, const float* __restrict__ w1,
                                const float* __restrict__ w2,
                                float* __restrict__ o0, float* __restrict__ o1,
                                float* __restrict__ o2) {
    int tid = blockIdx.x * 256 + threadIdx.x;
    if (tid >= NG * NH) return;
    int n = tid >> 3, h = tid & 7;
    const float4* r4 = (const float4*)&xg[(size_t)n * 128 + h * 16];
    const float4* a4 = (const float4*)&w0[h * 16];
    const float4* b4 = (const float4*)&w1[h * 16];
    const float4* c4 = (const float4*)&w2[h * 16];
    float s0 = 0.f, s1 = 0.f, s2 = 0.f;
    #pragma unroll
    for (int c = 0; c < 4; c++) {
        float4 v = r4[c], a = a4[c], b = b4[c], cc = c4[c];
        s0 += v.x * a.x + v.y * a.y + v.z * a.z + v.w * a.w;
        s1 += v.x * b.x + v.y * b.y + v.z * b.z + v.w * b.w;
        s2 += v.x * cc.x + v.y * cc.y + v.z * cc.z + v.w * cc.w;
    }
    o0[tid] = s0; o1[tid] = s1; o2[tid] = s2;
}

__launch_bounds__(256)
__global__ void att_scores_dis(const float* __restrict__ xd, const float* __restrict__ w0,
                               float* __restrict__ o0) {
    int tid = blockIdx.x * 256 + threadIdx.x;
    if (tid >= ND * NH) return;
    int n = tid >> 3, h = tid & 7;
    const float4* r4 = (const float4*)&xd[(size_t)n * 128 + h * 16];
    const float4* a4 = (const float4*)&w0[h * 16];
    float s0 = 0.f;
    #pragma unroll
    for (int c = 0; c < 4; c++) {
        float4 v = r4[c], a = a4[c];
        s0 += v.x * a.x + v.y * a.y + v.z * a.z + v.w * a.w;
    }
    o0[tid] = s0;
}

// ---------------- edge passes ----------------
__launch_bounds__(256)
__global__ void edge_logit_max(const int* __restrict__ es, const int* __restrict__ ed,
                               const float* __restrict__ a_s, const float* __restrict__ a_d,
                               float* __restrict__ m, int E) {
    int tid = blockIdx.x * 256 + threadIdx.x;
    if (tid >= E * NH) return;
    int e = tid >> 3, h = tid & 7;
    int s = es[e], d = ed[e];
    float a = a_s[s * NH + h] + a_d[d * NH + h];
    a = a > 0.f ? a : 0.2f * a;
    atomicMaxF(&m[d * NH + h], a);
}

__launch_bounds__(256)
__global__ void edge_exp_sum(const int* __restrict__ es, const int* __restrict__ ed,
                             const float* __restrict__ a_s, const float* __restrict__ a_d,
                             const float* __restrict__ m, float* __restrict__ ssum, int E) {
    int tid = blockIdx.x * 256 + threadIdx.x;
    if (tid >= E * NH) return;
    int e = tid >> 3, h = tid & 7;
    int s = es[e], d = ed[e];
    float a = a_s[s * NH + h] + a_d[d * NH + h];
    a = a > 0.f ? a : 0.2f * a;
    atomicAdd(&ssum[d * NH + h], expf(a - m[d * NH + h]));
}

__launch_bounds__(256)
__global__ void edge_message(const int* __restrict__ es, const int* __restrict__ ed,
                             const float* __restrict__ a_s, const float* __restrict__ a_d,
                             const float* __restrict__ m, const float* __restrict__ ssum,
                             const float* __restrict__ xsrc, float* __restrict__ outb,
                             int total) {
    int tid = blockIdx.x * 256 + threadIdx.x;
    if (tid >= total) return;
    int e = tid >> 7;
    int t = tid & 127;
    int h = t >> 4;
    int s = es[e], d = ed[e];
    float a = a_s[s * NH + h] + a_d[d * NH + h];
    a = a > 0.f ? a : 0.2f * a;
    float alpha = expf(a - m[d * NH + h]) / (ssum[d * NH + h] + 1e-16f);
    atomicAdd(&outb[(size_t)d * 128 + t], xsrc[(size_t)s * 128 + t] * alpha);
}

// ---------------- k = tanh(relu(out) @ Wk^T + bk); accumulate column sums ----------------
__launch_bounds__(256)
__global__ void kmean_gemm(const float* __restrict__ outbuf, const float* __restrict__ W,
                           const float* __restrict__ bias, float* __restrict__ kpart, int N) {
    __shared__ float Ws[128 * 132];
    __shared__ float rows[8][128];
    __shared__ float red[8][128];
    for (int idx = threadIdx.x; idx < 128 * 128; idx += 256) {
        int i = idx >> 7, j = idx & 127;
        Ws[i * 132 + j] = W[j * 128 + i];
    }
    __syncthreads();
    int g = threadIdx.x >> 5;
    int l = threadIdx.x & 31;
    float4 bvec = *(const float4*)&bias[l * 4];
    float4 accsum = make_float4(0.f, 0.f, 0.f, 0.f);
    for (int base = blockIdx.x * 8; base < N; base += gridDim.x * 8) {
        int n = base + g;
        if (n < N) {
            float4 v = *(const float4*)&outbuf[(size_t)n * 128 + l * 4];
            v.x = fmaxf(v.x, 0.f); v.y = fmaxf(v.y, 0.f);
            v.z = fmaxf(v.z, 0.f); v.w = fmaxf(v.w, 0.f);
            *(float4*)&rows[g][l * 4] = v;
        }
        __syncthreads();
        if (n < N) {
            float4 acc = bvec;
            #pragma unroll 8
            for (int i = 0; i < 128; i++) {
                float r = rows[g][i];
                float4 w = *(const float4*)&Ws[i * 132 + l * 4];
                acc.x += r * w.x; acc.y += r * w.y; acc.z += r * w.z; acc.w += r * w.w;
            }
            accsum.x += tanhf(acc.x); accsum.y += tanhf(acc.y);
            accsum.z += tanhf(acc.z); accsum.w += tanhf(acc.w);
        }
        __syncthreads();
    }
    *(float4*)&red[g][l * 4] = accsum;
    __syncthreads();
    if (threadIdx.x < 128) {
        float sum = 0.f;
        #pragma unroll
        for (int gg = 0; gg < 8; gg++) sum += red[gg][threadIdx.x];
        atomicAdd(&kpart[threadIdx.x], sum);
    }
}

// ---------------- semantic softmax (2 scores) ----------------
__global__ void score_attn(const float* __restrict__ kpart, const float* __restrict__ q,
                           float* __restrict__ attn) {
    __shared__ float r0[128], r1[128];
    int t = threadIdx.x;
    r0[t] = q[t] * kpart[t];
    r1[t] = q[t] * kpart[128 + t];
    __syncthreads();
    for (int s = 64; s > 0; s >>= 1) {
        if (t < s) { r0[t] += r0[t + s]; r1[t] += r1[t + s]; }
        __syncthreads();
    }
    if (t == 0) {
        float s0 = r0[0] / (float)NG, s1 = r1[0] / (float)NG;
        float mx = fmaxf(s0, s1);
        float e0 = expf(s0 - mx), e1 = expf(s1 - mx);
        attn[0] = e0 / (e0 + e1);
        attn[1] = e1 / (e0 + e1);
    }
}

// ---------------- fused combine + final linear [NG,2] ----------------
__launch_bounds__(256)
__global__ void final_lin(const float* __restrict__ gg, const float* __restrict__ dgb,
                          const float* __restrict__ attn, const float* __restrict__ lin_w,
                          const float* __restrict__ lin_b, float* __restrict__ outp) {
    __shared__ float wsum[4][2];
    int half = threadIdx.x >> 7;
    int j = threadIdx.x & 127;
    int node = blockIdx.x * 2 + half;
    float a0 = attn[0], a1 = attn[1];
    float p0 = 0.f, p1 = 0.f;
    if (node < NG) {
        float f = a0 * fmaxf(gg[(size_t)node * 128 + j], 0.f)
                + a1 * fmaxf(dgb[(size_t)node * 128 + j], 0.f);
        p0 = f * lin_w[j];
        p1 = f * lin_w[128 + j];
    }
    for (int off = 32; off > 0; off >>= 1) {
        p0 += __shfl_down(p0, off);
        p1 += __shfl_down(p1, off);
    }
    int wave = threadIdx.x >> 6;
    if ((threadIdx.x & 63) == 0) { wsum[wave][0] = p0; wsum[wave][1] = p1; }
    __syncthreads();
    if ((threadIdx.x & 127) == 0 && node < NG) {
        float s0 = wsum[half * 2][0] + wsum[half * 2 + 1][0] + lin_b[0];
        float s1 = wsum[half * 2][1] + wsum[half * 2 + 1][1] + lin_b[1];
        outp[node * 2 + 0] = s0;
        outp[node * 2 + 1] = s1;
    }
}

extern "C" void kernel_launch(void* const* d_in, const int* in_sizes, int n_in,
                              void* d_out, int out_size, void* d_ws, size_t ws_size,
                              hipStream_t stream) {
    const float* x_gene    = (const float*)d_in[0];
    const float* x_disease = (const float*)d_in[1];
    const int*   edge_gg   = (const int*)d_in[2];
    const int*   edge_dg   = (const int*)d_in[3];
    const float* pg_w      = (const float*)d_in[4];
    const float* pg_b      = (const float*)d_in[5];
    const float* pd_w      = (const float*)d_in[6];
    const float* pd_b      = (const float*)d_in[7];
    const float* att_src_gg= (const float*)d_in[8];
    const float* att_dst_gg= (const float*)d_in[9];
    const float* att_src_dg= (const float*)d_in[10];
    const float* att_dst_dg= (const float*)d_in[11];
    const float* k_lin_w   = (const float*)d_in[12];
    const float* k_lin_b   = (const float*)d_in[13];
    const float* q         = (const float*)d_in[14];
    const float* lin_w     = (const float*)d_in[15];
    const float* lin_b     = (const float*)d_in[16];
    float* out = (float*)d_out;
    float* ws  = (float*)d_ws;

    float* out_gg = ws + OFF_OUT_GG;
    float* out_dg = ws + OFF_OUT_DG;
    float* s_gg   = ws + OFF_S_GG;
    float* s_dg   = ws + OFF_S_DG;
    float* kpart  = ws + OFF_KPART;
    float* m_gg   = ws + OFF_M_GG;
    float* m_dg   = ws + OFF_M_DG;
    float* xg     = ws + OFF_XG;
    float* xd     = ws + OFF_XD;
    float* a_src_gg = ws + OFF_ASG;
    float* a_dst_gg = ws + OFF_ADG;
    float* a_dst_dg = ws + OFF_ADD;
    float* a_src_dg = ws + OFF_ASD;
    float* attn   = ws + OFF_ATTN;

    // 1. init workspace (zeros + -inf spans)
    {
        int n4 = (int)(NINF_END / 4);
        int grid = (n4 + 255) / 256;
        hipLaunchKernelGGL(init_ws_k, dim3(grid), dim3(256), 0, stream, (float4*)ws);
    }
    // 2. projections
    hipLaunchKernelGGL(proj_gemm, dim3(512), dim3(256), 0, stream, x_gene, pg_w, pg_b, xg, NG);
    hipLaunchKernelGGL(proj_gemm, dim3(512), dim3(256), 0, stream, x_disease, pd_w, pd_b, xd, ND);
    // 3. per-node logit halves
    hipLaunchKernelGGL(att_scores_gene, dim3((NG * NH + 255) / 256), dim3(256), 0, stream,
                       xg, att_src_gg, att_dst_gg, att_dst_dg, a_src_gg, a_dst_gg, a_dst_dg);
    hipLaunchKernelGGL(att_scores_dis, dim3((ND * NH + 255) / 256), dim3(256), 0, stream,
                       xd, att_src_dg, a_src_dg);
    // 4. gg edge type
    const int* gg_src = edge_gg;
    const int* gg_dst = edge_gg + EGG;
    hipLaunchKernelGGL(edge_logit_max, dim3(EGG * NH / 256), dim3(256), 0, stream,
                       gg_src, gg_dst, a_src_gg, a_dst_gg, m_gg, EGG);
    hipLaunchKernelGGL(edge_exp_sum, dim3(EGG * NH / 256), dim3(256), 0, stream,
                       gg_src, gg_dst, a_src_gg, a_dst_gg, m_gg, s_gg, EGG);
    hipLaunchKernelGGL(edge_message, dim3(EGG * 128 / 256), dim3(256), 0, stream,
                       gg_src, gg_dst, a_src_gg, a_dst_gg, m_gg, s_gg, xg, out_gg, EGG * 128);
    // 5. dg edge type
    const int* dg_src = edge_dg;
    const int* dg_dst = edge_dg + EDG;
    hipLaunchKernelGGL(edge_logit_max, dim3(EDG * NH / 256), dim3(256), 0, stream,
                       dg_src, dg_dst, a_src_dg, a_dst_dg, m_dg, EDG);
    hipLaunchKernelGGL(edge_exp_sum, dim3(EDG * NH / 256), dim3(256), 0, stream,
                       dg_src, dg_dst, a_src_dg, a_dst_dg, m_dg, s_dg, EDG);
    hipLaunchKernelGGL(edge_message, dim3(EDG * 128 / 256), dim3(256), 0, stream,
                       dg_src, dg_dst, a_src_dg, a_dst_dg, m_dg, s_dg, xd, out_dg, EDG * 128);
    // 6. semantic attention
    hipLaunchKernelGGL(kmean_gemm, dim3(512), dim3(256), 0, stream, out_gg, k_lin_w, k_lin_b, kpart, NG);
    hipLaunchKernelGGL(kmean_gemm, dim3(512), dim3(256), 0, stream, out_dg, k_lin_w, k_lin_b, kpart + 128, NG);
    hipLaunchKernelGGL(score_attn, dim3(1), dim3(128), 0, stream, kpart, q, attn);
    // 7. fused combine + final linear
    hipLaunchKernelGGL(final_lin, dim3((NG + 1) / 2), dim3(256), 0, stream,
                       out_gg, out_dg, attn, lin_w, lin_b, out);
}

// Round 2
// 909.174 us; speedup vs baseline: 1.9795x; 1.9795x over previous
//
#include <hip/hip_runtime.h>
#include <math.h>

#define NG 100000
#define ND 50000
#define EGG 1600000
#define EDG 800000
#define HID 128
#define NH 8

// ---------------- workspace layout (4-byte element offsets) ----------------
#define OFF_OUT_GG 0UL          // 12,800,000 f  (written fully by gat_gather)
#define OFF_OUT_DG 12800000UL   // 12,800,000 f
#define OFF_XG     25600000UL   // 12,800,000 f
#define OFF_XD     38400000UL   //  6,400,000 f
#define OFF_ASG    44800000UL   //    800,000 f  a_src_gg [NG,8]
#define OFF_ADG    45600000UL   //    800,000 f  a_dst_gg [NG,8]
#define OFF_ADD    46400000UL   //    800,000 f  a_dst_dg [NG,8]
#define OFF_ASD    47200000UL   //    400,000 f  a_src_dg [ND,8]
#define OFF_KPART  47600000UL   //        256 f  (zero-init)
#define OFF_DEG_GG 47600256UL   //    100,000 i  (zero-init)
#define OFF_DEG_DG 47700256UL   //    100,000 i  (zero-init)
#define ZERO_BASE  OFF_KPART
#define ZERO_CNT   200256
#define OFF_ATTN   47800256UL   //          2 f (+pad)
#define OFF_RP_GG  47800272UL   //    100,001 i
#define OFF_RP_DG  47900288UL   //    100,001 i
#define OFF_CUR_GG 48000304UL   //    100,000 i
#define OFF_CUR_DG 48100304UL   //    100,000 i
#define OFF_BSUM   48200304UL   //        128 i
#define OFF_COL_GG 48200432UL   //  1,600,000 i
#define OFF_COL_DG 49800432UL   //    800,000 i
// end: 50,600,432 elems = 202.4 MB

// ---------------- init: zero kpart + degree arrays ----------------
__global__ void init_zero_k(float* __restrict__ p, int n) {
    int i = blockIdx.x * 256 + threadIdx.x;
    if (i < n) p[i] = 0.f;
}

// ---------------- projection GEMM: out[n,j] = b[j] + sum_i x[n,i]*W[j,i] ----------------
__launch_bounds__(256)
__global__ void proj_gemm(const float* __restrict__ x, const float* __restrict__ W,
                          const float* __restrict__ bias, float* __restrict__ out, int N) {
    __shared__ float Ws[128 * 132];     // Ws[i*132 + j] = W[j*128 + i]
    __shared__ float rows[8][128];
    for (int idx = threadIdx.x; idx < 128 * 128; idx += 256) {
        int i = idx >> 7, j = idx & 127;
        Ws[i * 132 + j] = W[j * 128 + i];
    }
    __syncthreads();
    int g = threadIdx.x >> 5;
    int l = threadIdx.x & 31;
    float4 bvec = *(const float4*)&bias[l * 4];
    for (int base = blockIdx.x * 8; base < N; base += gridDim.x * 8) {
        int n = base + g;
        if (n < N) {
            float4 v = *(const float4*)&x[(size_t)n * 128 + l * 4];
            *(float4*)&rows[g][l * 4] = v;
        }
        __syncthreads();
        if (n < N) {
            float4 acc = bvec;
            #pragma unroll 8
            for (int i = 0; i < 128; i++) {
                float r = rows[g][i];
                float4 w = *(const float4*)&Ws[i * 132 + l * 4];
                acc.x += r * w.x; acc.y += r * w.y; acc.z += r * w.z; acc.w += r * w.w;
            }
            *(float4*)&out[(size_t)n * 128 + l * 4] = acc;
        }
        __syncthreads();
    }
}

// ---------------- per-node attention logit halves ----------------
__launch_bounds__(256)
__global__ void att_scores_gene(const float* __restrict__ xg,
                                const float* __restrict__ w0, const float* __restrict__ w1,
                                const float* __restrict__ w2,
                                float* __restrict__ o0, float* __restrict__ o1,
                                float* __restrict__ o2) {
    int tid = blockIdx.x * 256 + threadIdx.x;
    if (tid >= NG * NH) return;
    int n = tid >> 3, h = tid & 7;
    const float4* r4 = (const float4*)&xg[(size_t)n * 128 + h * 16];
    const float4* a4 = (const float4*)&w0[h * 16];
    const float4* b4 = (const float4*)&w1[h * 16];
    const float4* c4 = (const float4*)&w2[h * 16];
    float s0 = 0.f, s1 = 0.f, s2 = 0.f;
    #pragma unroll
    for (int c = 0; c < 4; c++) {
        float4 v = r4[c], a = a4[c], b = b4[c], cc = c4[c];
        s0 += v.x * a.x + v.y * a.y + v.z * a.z + v.w * a.w;
        s1 += v.x * b.x + v.y * b.y + v.z * b.z + v.w * b.w;
        s2 += v.x * cc.x + v.y * cc.y + v.z * cc.z + v.w * cc.w;
    }
    o0[tid] = s0; o1[tid] = s1; o2[tid] = s2;
}

__launch_bounds__(256)
__global__ void att_scores_dis(const float* __restrict__ xd, const float* __restrict__ w0,
                               float* __restrict__ o0) {
    int tid = blockIdx.x * 256 + threadIdx.x;
    if (tid >= ND * NH) return;
    int n = tid >> 3, h = tid & 7;
    const float4* r4 = (const float4*)&xd[(size_t)n * 128 + h * 16];
    const float4* a4 = (const float4*)&w0[h * 16];
    float s0 = 0.f;
    #pragma unroll
    for (int c = 0; c < 4; c++) {
        float4 v = r4[c], a = a4[c];
        s0 += v.x * a.x + v.y * a.y + v.z * a.z + v.w * a.w;
    }
    o0[tid] = s0;
}

// ---------------- CSR build ----------------
__global__ void count_deg(const int* __restrict__ dst, int* __restrict__ deg, int E) {
    int e = blockIdx.x * 256 + threadIdx.x;
    if (e < E) atomicAdd(&deg[dst[e]], 1);
}

// block scans 1024 elements (4/thread)
__global__ void scan1(const int* __restrict__ deg, int* __restrict__ rp,
                      int* __restrict__ bsum, int N) {
    __shared__ int tsum[256];
    int t = threadIdx.x;
    int base = blockIdx.x * 1024 + t * 4;
    int v0 = 0, v1 = 0, v2 = 0, v3 = 0;
    if (base + 0 < N) v0 = deg[base + 0];
    if (base + 1 < N) v1 = deg[base + 1];
    if (base + 2 < N) v2 = deg[base + 2];
    if (base + 3 < N) v3 = deg[base + 3];
    int tot = v0 + v1 + v2 + v3;
    tsum[t] = tot;
    __syncthreads();
    for (int off = 1; off < 256; off <<= 1) {
        int y = (t >= off) ? tsum[t - off] : 0;
        __syncthreads();
        tsum[t] += y;
        __syncthreads();
    }
    int excl = tsum[t] - tot;   // exclusive prefix of this thread's chunk within block
    if (base + 0 < N) rp[base + 0] = excl;
    if (base + 1 < N) rp[base + 1] = excl + v0;
    if (base + 2 < N) rp[base + 2] = excl + v0 + v1;
    if (base + 3 < N) rp[base + 3] = excl + v0 + v1 + v2;
    if (t == 255) bsum[blockIdx.x] = tsum[255];
}

__global__ void scan2(int* __restrict__ bsum, int NB) {
    __shared__ int s[128];
    int t = threadIdx.x;
    int v = (t < NB) ? bsum[t] : 0;
    s[t] = v;
    __syncthreads();
    for (int off = 1; off < 128; off <<= 1) {
        int y = (t >= off) ? s[t - off] : 0;
        __syncthreads();
        s[t] += y;
        __syncthreads();
    }
    if (t < NB) bsum[t] = s[t] - v;   // exclusive
}

__global__ void scan3(int* __restrict__ rp, const int* __restrict__ bsum,
                      int* __restrict__ cur, int N, int E) {
    int i = blockIdx.x * 256 + threadIdx.x;
    if (i < N) {
        int v = rp[i] + bsum[i >> 10];
        rp[i] = v;
        cur[i] = v;
    }
    if (i == 0) rp[N] = E;
}

__global__ void scatter_edges(const int* __restrict__ src, const int* __restrict__ dst,
                              int* __restrict__ cur, int* __restrict__ col, int E) {
    int e = blockIdx.x * 256 + threadIdx.x;
    if (e < E) {
        int d = dst[e];
        int pos = atomicAdd(&cur[d], 1);
        col[pos] = src[e];
    }
}

// ---------------- fused GAT gather: one wave per dst node ----------------
// phase 1: online softmax (max,sum) per head over this node's edges
// phase 2: accumulate alpha * x_src rows, single coalesced write
__launch_bounds__(256)
__global__ void gat_gather(const int* __restrict__ rp, const int* __restrict__ col,
                           const float* __restrict__ a_s, const float* __restrict__ a_d,
                           const float* __restrict__ xsrc, float* __restrict__ outb,
                           int ndst) {
    int wid = (blockIdx.x * 256 + threadIdx.x) >> 6;
    int l = threadIdx.x & 63;
    if (wid >= ndst) return;
    int d = wid;
    int base = rp[d];
    int deg = rp[d + 1] - base;

    int hl = l & 7;          // phase-1: this lane's head
    int g  = l >> 3;         // phase-1: this lane's edge subgroup (stride 8)
    float adl = a_d[d * 8 + hl];
    float m = -1e30f, ssum = 0.f;
    for (int c0 = 0; c0 < deg; c0 += 64) {
        int myi = c0 + l;
        int colreg = (myi < deg) ? col[base + myi] : 0;
        int lim = min(deg - c0, 64);
        for (int t = g; t < lim; t += 8) {
            int s = __shfl(colreg, t);
            float a = a_s[s * 8 + hl] + adl;
            a = a > 0.f ? a : 0.2f * a;
            float nm = fmaxf(m, a);
            ssum = ssum * __expf(m - nm) + __expf(a - nm);
            m = nm;
        }
    }
    // reduce (m,ssum) across the 8 lanes sharing each head (stride-8 groups)
    for (int off = 8; off < 64; off <<= 1) {
        float m2 = __shfl_xor(m, off);
        float s2 = __shfl_xor(ssum, off);
        float nm = fmaxf(m, m2);
        ssum = ssum * __expf(m - nm) + s2 * __expf(m2 - nm);
        m = nm;
    }
    // redistribute to phase-2 layout: lane l covers cols 2l,2l+1; head = l>>3
    int hc = l >> 3;
    float mc  = __shfl(m, hc);
    float sc  = __shfl(ssum, hc);
    float adc = __shfl(adl, hc);

    float accx = 0.f, accy = 0.f;
    for (int c0 = 0; c0 < deg; c0 += 64) {
        int myi = c0 + l;
        int colreg = (myi < deg) ? col[base + myi] : 0;
        int lim = min(deg - c0, 64);
        for (int t = 0; t < lim; ++t) {
            int s = __shfl(colreg, t);
            float a = a_s[s * 8 + hc] + adc;
            a = a > 0.f ? a : 0.2f * a;
            float alpha = __expf(a - mc) / (sc + 1e-16f);
            float2 x = *(const float2*)&xsrc[(size_t)s * 128 + l * 2];
            accx += alpha * x.x;
            accy += alpha * x.y;
        }
    }
    float2 o; o.x = accx; o.y = accy;
    *(float2*)&outb[(size_t)d * 128 + l * 2] = o;   // deg==0 rows get zeros
}

// ---------------- k = tanh(relu(out) @ Wk^T + bk); accumulate column sums ----------------
__launch_bounds__(256)
__global__ void kmean_gemm(const float* __restrict__ outbuf, const float* __restrict__ W,
                           const float* __restrict__ bias, float* __restrict__ kpart, int N) {
    __shared__ float Ws[128 * 132];
    __shared__ float rows[8][128];
    __shared__ float red[8][128];
    for (int idx = threadIdx.x; idx < 128 * 128; idx += 256) {
        int i = idx >> 7, j = idx & 127;
        Ws[i * 132 + j] = W[j * 128 + i];
    }
    __syncthreads();
    int g = threadIdx.x >> 5;
    int l = threadIdx.x & 31;
    float4 bvec = *(const float4*)&bias[l * 4];
    float4 accsum = make_float4(0.f, 0.f, 0.f, 0.f);
    for (int base = blockIdx.x * 8; base < N; base += gridDim.x * 8) {
        int n = base + g;
        if (n < N) {
            float4 v = *(const float4*)&outbuf[(size_t)n * 128 + l * 4];
            v.x = fmaxf(v.x, 0.f); v.y = fmaxf(v.y, 0.f);
            v.z = fmaxf(v.z, 0.f); v.w = fmaxf(v.w, 0.f);
            *(float4*)&rows[g][l * 4] = v;
        }
        __syncthreads();
        if (n < N) {
            float4 acc = bvec;
            #pragma unroll 8
            for (int i = 0; i < 128; i++) {
                float r = rows[g][i];
                float4 w = *(const float4*)&Ws[i * 132 + l * 4];
                acc.x += r * w.x; acc.y += r * w.y; acc.z += r * w.z; acc.w += r * w.w;
            }
            accsum.x += tanhf(acc.x); accsum.y += tanhf(acc.y);
            accsum.z += tanhf(acc.z); accsum.w += tanhf(acc.w);
        }
        __syncthreads();
    }
    *(float4*)&red[g][l * 4] = accsum;
    __syncthreads();
    if (threadIdx.x < 128) {
        float sum = 0.f;
        #pragma unroll
        for (int gg = 0; gg < 8; gg++) sum += red[gg][threadIdx.x];
        atomicAdd(&kpart[threadIdx.x], sum);
    }
}

// ---------------- semantic softmax (2 scores) ----------------
__global__ void score_attn(const float* __restrict__ kpart, const float* __restrict__ q,
                           float* __restrict__ attn) {
    __shared__ float r0[128], r1[128];
    int t = threadIdx.x;
    r0[t] = q[t] * kpart[t];
    r1[t] = q[t] * kpart[128 + t];
    __syncthreads();
    for (int s = 64; s > 0; s >>= 1) {
        if (t < s) { r0[t] += r0[t + s]; r1[t] += r1[t + s]; }
        __syncthreads();
    }
    if (t == 0) {
        float s0 = r0[0] / (float)NG, s1 = r1[0] / (float)NG;
        float mx = fmaxf(s0, s1);
        float e0 = expf(s0 - mx), e1 = expf(s1 - mx);
        attn[0] = e0 / (e0 + e1);
        attn[1] = e1 / (e0 + e1);
    }
}

// ---------------- fused combine + final linear [NG,2] ----------------
__launch_bounds__(256)
__global__ void final_lin(const float* __restrict__ gg, const float* __restrict__ dgb,
                          const float* __restrict__ attn, const float* __restrict__ lin_w,
                          const float* __restrict__ lin_b, float* __restrict__ outp) {
    __shared__ float wsum[4][2];
    int half = threadIdx.x >> 7;
    int j = threadIdx.x & 127;
    int node = blockIdx.x * 2 + half;
    float a0 = attn[0], a1 = attn[1];
    float p0 = 0.f, p1 = 0.f;
    if (node < NG) {
        float f = a0 * fmaxf(gg[(size_t)node * 128 + j], 0.f)
                + a1 * fmaxf(dgb[(size_t)node * 128 + j], 0.f);
        p0 = f * lin_w[j];
        p1 = f * lin_w[128 + j];
    }
    for (int off = 32; off > 0; off >>= 1) {
        p0 += __shfl_down(p0, off);
        p1 += __shfl_down(p1, off);
    }
    int wave = threadIdx.x >> 6;
    if ((threadIdx.x & 63) == 0) { wsum[wave][0] = p0; wsum[wave][1] = p1; }
    __syncthreads();
    if ((threadIdx.x & 127) == 0 && node < NG) {
        float s0 = wsum[half * 2][0] + wsum[half * 2 + 1][0] + lin_b[0];
        float s1 = wsum[half * 2][1] + wsum[half * 2 + 1][1] + lin_b[1];
        outp[node * 2 + 0] = s0;
        outp[node * 2 + 1] = s1;
    }
}

extern "C" void kernel_launch(void* const* d_in, const int* in_sizes, int n_in,
                              void* d_out, int out_size, void* d_ws, size_t ws_size,
                              hipStream_t stream) {
    const float* x_gene    = (const float*)d_in[0];
    const float* x_disease = (const float*)d_in[1];
    const int*   edge_gg   = (const int*)d_in[2];
    const int*   edge_dg   = (const int*)d_in[3];
    const float* pg_w      = (const float*)d_in[4];
    const float* pg_b      = (const float*)d_in[5];
    const float* pd_w      = (const float*)d_in[6];
    const float* pd_b      = (const float*)d_in[7];
    const float* att_src_gg= (const float*)d_in[8];
    const float* att_dst_gg= (const float*)d_in[9];
    const float* att_src_dg= (const float*)d_in[10];
    const float* att_dst_dg= (const float*)d_in[11];
    const float* k_lin_w   = (const float*)d_in[12];
    const float* k_lin_b   = (const float*)d_in[13];
    const float* q         = (const float*)d_in[14];
    const float* lin_w     = (const float*)d_in[15];
    const float* lin_b     = (const float*)d_in[16];
    float* out = (float*)d_out;
    float* ws  = (float*)d_ws;

    float* out_gg = ws + OFF_OUT_GG;
    float* out_dg = ws + OFF_OUT_DG;
    float* xg     = ws + OFF_XG;
    float* xd     = ws + OFF_XD;
    float* a_src_gg = ws + OFF_ASG;
    float* a_dst_gg = ws + OFF_ADG;
    float* a_dst_dg = ws + OFF_ADD;
    float* a_src_dg = ws + OFF_ASD;
    float* kpart  = ws + OFF_KPART;
    float* attn   = ws + OFF_ATTN;
    int* deg_gg = (int*)(ws + OFF_DEG_GG);
    int* deg_dg = (int*)(ws + OFF_DEG_DG);
    int* rp_gg  = (int*)(ws + OFF_RP_GG);
    int* rp_dg  = (int*)(ws + OFF_RP_DG);
    int* cur_gg = (int*)(ws + OFF_CUR_GG);
    int* cur_dg = (int*)(ws + OFF_CUR_DG);
    int* bsum   = (int*)(ws + OFF_BSUM);
    int* col_gg = (int*)(ws + OFF_COL_GG);
    int* col_dg = (int*)(ws + OFF_COL_DG);

    const int* gg_src = edge_gg;
    const int* gg_dst = edge_gg + EGG;
    const int* dg_src = edge_dg;
    const int* dg_dst = edge_dg + EDG;

    // 1. zero kpart + degree arrays
    hipLaunchKernelGGL(init_zero_k, dim3((ZERO_CNT + 255) / 256), dim3(256), 0, stream,
                       ws + ZERO_BASE, ZERO_CNT);
    // 2. projections
    hipLaunchKernelGGL(proj_gemm, dim3(512), dim3(256), 0, stream, x_gene, pg_w, pg_b, xg, NG);
    hipLaunchKernelGGL(proj_gemm, dim3(512), dim3(256), 0, stream, x_disease, pd_w, pd_b, xd, ND);
    // 3. per-node logit halves
    hipLaunchKernelGGL(att_scores_gene, dim3((NG * NH + 255) / 256), dim3(256), 0, stream,
                       xg, att_src_gg, att_dst_gg, att_dst_dg, a_src_gg, a_dst_gg, a_dst_dg);
    hipLaunchKernelGGL(att_scores_dis, dim3((ND * NH + 255) / 256), dim3(256), 0, stream,
                       xd, att_src_dg, a_src_dg);
    // 4. CSR build + fused gather, gg
    hipLaunchKernelGGL(count_deg, dim3((EGG + 255) / 256), dim3(256), 0, stream, gg_dst, deg_gg, EGG);
    hipLaunchKernelGGL(scan1, dim3((NG + 1023) / 1024), dim3(256), 0, stream, deg_gg, rp_gg, bsum, NG);
    hipLaunchKernelGGL(scan2, dim3(1), dim3(128), 0, stream, bsum, (NG + 1023) / 1024);
    hipLaunchKernelGGL(scan3, dim3((NG + 255) / 256), dim3(256), 0, stream, rp_gg, bsum, cur_gg, NG, EGG);
    hipLaunchKernelGGL(scatter_edges, dim3((EGG + 255) / 256), dim3(256), 0, stream,
                       gg_src, gg_dst, cur_gg, col_gg, EGG);
    hipLaunchKernelGGL(gat_gather, dim3((NG + 3) / 4), dim3(256), 0, stream,
                       rp_gg, col_gg, a_src_gg, a_dst_gg, xg, out_gg, NG);
    // 5. CSR build + fused gather, dg (bsum reused; stream-serialized)
    hipLaunchKernelGGL(count_deg, dim3((EDG + 255) / 256), dim3(256), 0, stream, dg_dst, deg_dg, EDG);
    hipLaunchKernelGGL(scan1, dim3((NG + 1023) / 1024), dim3(256), 0, stream, deg_dg, rp_dg, bsum, NG);
    hipLaunchKernelGGL(scan2, dim3(1), dim3(128), 0, stream, bsum, (NG + 1023) / 1024);
    hipLaunchKernelGGL(scan3, dim3((NG + 255) / 256), dim3(256), 0, stream, rp_dg, bsum, cur_dg, NG, EDG);
    hipLaunchKernelGGL(scatter_edges, dim3((EDG + 255) / 256), dim3(256), 0, stream,
                       dg_src, dg_dst, cur_dg, col_dg, EDG);
    hipLaunchKernelGGL(gat_gather, dim3((NG + 3) / 4), dim3(256), 0, stream,
                       rp_dg, col_dg, a_src_dg, a_dst_dg, xd, out_dg, NG);
    // 6. semantic attention
    hipLaunchKernelGGL(kmean_gemm, dim3(512), dim3(256), 0, stream, out_gg, k_lin_w, k_lin_b, kpart, NG);
    hipLaunchKernelGGL(kmean_gemm, dim3(512), dim3(256), 0, stream, out_dg, k_lin_w, k_lin_b, kpart + 128, NG);
    hipLaunchKernelGGL(score_attn, dim3(1), dim3(128), 0, stream, kpart, q, attn);
    // 7. fused combine + final linear
    hipLaunchKernelGGL(final_lin, dim3((NG + 1) / 2), dim3(256), 0, stream,
                       out_gg, out_dg, attn, lin_w, lin_b, out);
}

// Round 3
// 811.871 us; speedup vs baseline: 2.2168x; 1.1198x over previous
//
#include <hip/hip_runtime.h>
#include <math.h>

#define NG 100000
#define ND 50000
#define EGG 1600000
#define EDG 800000
#define EALL (EGG + EDG)
#define NALL (NG + NG)
#define HID 128
#define NH 8

// ---------------- workspace layout (4-byte element offsets) ----------------
#define OFF_OUT_GG 0UL          // 12,800,000
#define OFF_OUT_DG 12800000UL   // 12,800,000
#define OFF_XG     25600000UL   // 12,800,000
#define OFF_XD     38400000UL   //  6,400,000
#define OFF_ASG    44800000UL   //    800,000  a_src_gg [NG,8]
#define OFF_ADG    45600000UL   //    800,000  a_dst_gg [NG,8]
#define OFF_ADD    46400000UL   //    800,000  a_dst_dg [NG,8]
#define OFF_ASD    47200000UL   //    400,000  a_src_dg [ND,8]
#define OFF_KPART  47600000UL   //        256  (zero-init)
#define OFF_DEG    47600256UL   //    200,000  (zero-init) [gg | dg]
#define ZERO_BASE  OFF_KPART
#define ZERO_CNT   200256
#define OFF_ATTN   47800256UL   //          2 (+pad)
#define OFF_RP     47800272UL   //    200,001 (+pad to 200,008)
#define OFF_CUR    48000280UL   //    200,000
#define OFF_BSUM   48200280UL   //        256
#define OFF_COL    48200536UL   //  2,400,000  [gg edges | dg edges]
// end: 50,600,536 elems = 202.4 MB

__device__ __forceinline__ float fast_tanh(float x) {
    x = fminf(fmaxf(x, -15.f), 15.f);
    float t = __expf(2.f * x);
    return (t - 1.f) / (t + 1.f);
}

// ---------------- init ----------------
__global__ void init_zero_k(float* __restrict__ p, int n) {
    int i = blockIdx.x * 256 + threadIdx.x;
    if (i < n) p[i] = 0.f;
}

// ---------------- projection GEMM + fused attention-logit epilogue ----------------
// out[n,j] = b[j] + sum_i x[n,i]*W[j,i]; o_k[n,h] = sum_{c in head h} out[n,c]*att_k[c]
__launch_bounds__(256)
__global__ void proj_gemm_fused(const float* __restrict__ x, const float* __restrict__ W,
                                const float* __restrict__ bias, float* __restrict__ out, int N,
                                int natt,
                                const float* __restrict__ att0, const float* __restrict__ att1,
                                const float* __restrict__ att2,
                                float* __restrict__ o0, float* __restrict__ o1,
                                float* __restrict__ o2) {
    __shared__ float Ws[128 * 128];       // Ws[i*128 + j] = W[j*128 + i]
    __shared__ float rows_s[32][128];
    for (int idx = threadIdx.x; idx < 128 * 128; idx += 256) {
        int i = idx >> 7, j = idx & 127;
        Ws[i * 128 + j] = W[j * 128 + i];
    }
    int g = threadIdx.x >> 5;   // group 0..7, 4 rows each
    int l = threadIdx.x & 31;
    int g4 = g * 4;
    float4 bvec = *(const float4*)&bias[l * 4];
    float4 at0 = {0,0,0,0}, at1 = {0,0,0,0}, at2 = {0,0,0,0};
    if (natt > 0) at0 = *(const float4*)&att0[l * 4];
    if (natt > 1) at1 = *(const float4*)&att1[l * 4];
    if (natt > 2) at2 = *(const float4*)&att2[l * 4];
    __syncthreads();
    for (int base = blockIdx.x * 32; base < N; base += gridDim.x * 32) {
        int r0 = base + g4;
        #pragma unroll
        for (int k = 0; k < 4; k++) {
            int n = r0 + k;
            if (n < N)
                *(float4*)&rows_s[g4 + k][l * 4] = *(const float4*)&x[(size_t)n * 128 + l * 4];
        }
        __syncthreads();
        float4 acc0 = bvec, acc1 = bvec, acc2 = bvec, acc3 = bvec;
        #pragma unroll 4
        for (int i = 0; i < 128; i++) {
            float4 w = *(const float4*)&Ws[i * 128 + l * 4];
            float x0 = rows_s[g4 + 0][i];
            float x1 = rows_s[g4 + 1][i];
            float x2 = rows_s[g4 + 2][i];
            float x3 = rows_s[g4 + 3][i];
            acc0.x += x0 * w.x; acc0.y += x0 * w.y; acc0.z += x0 * w.z; acc0.w += x0 * w.w;
            acc1.x += x1 * w.x; acc1.y += x1 * w.y; acc1.z += x1 * w.z; acc1.w += x1 * w.w;
            acc2.x += x2 * w.x; acc2.y += x2 * w.y; acc2.z += x2 * w.z; acc2.w += x2 * w.w;
            acc3.x += x3 * w.x; acc3.y += x3 * w.y; acc3.z += x3 * w.z; acc3.w += x3 * w.w;
        }
        #define ROW_EPI(ACC, KK) do { \
            int n = r0 + KK; \
            if (n < N) { \
                *(float4*)&out[(size_t)n * 128 + l * 4] = ACC; \
                if (natt > 0) { \
                    float p = ACC.x*at0.x + ACC.y*at0.y + ACC.z*at0.z + ACC.w*at0.w; \
                    p += __shfl_xor(p, 1); p += __shfl_xor(p, 2); \
                    if ((l & 3) == 0) o0[n * 8 + (l >> 2)] = p; } \
                if (natt > 1) { \
                    float p = ACC.x*at1.x + ACC.y*at1.y + ACC.z*at1.z + ACC.w*at1.w; \
                    p += __shfl_xor(p, 1); p += __shfl_xor(p, 2); \
                    if ((l & 3) == 0) o1[n * 8 + (l >> 2)] = p; } \
                if (natt > 2) { \
                    float p = ACC.x*at2.x + ACC.y*at2.y + ACC.z*at2.z + ACC.w*at2.w; \
                    p += __shfl_xor(p, 1); p += __shfl_xor(p, 2); \
                    if ((l & 3) == 0) o2[n * 8 + (l >> 2)] = p; } \
            } } while (0)
        ROW_EPI(acc0, 0); ROW_EPI(acc1, 1); ROW_EPI(acc2, 2); ROW_EPI(acc3, 3);
        #undef ROW_EPI
        __syncthreads();
    }
}

// ---------------- CSR build (both edge types concatenated: nodes [0,NG)=gg, [NG,2NG)=dg) ----------------
__global__ void count_all(const int* __restrict__ gg_dst, const int* __restrict__ dg_dst,
                          int* __restrict__ deg) {
    int e = blockIdx.x * 256 + threadIdx.x;
    if (e < EGG) atomicAdd(&deg[gg_dst[e]], 1);
    else if (e < EALL) atomicAdd(&deg[NG + dg_dst[e - EGG]], 1);
}

__global__ void scan1(const int* __restrict__ deg, int* __restrict__ rp,
                      int* __restrict__ bsum, int N) {
    __shared__ int tsum[256];
    int t = threadIdx.x;
    int base = blockIdx.x * 1024 + t * 4;
    int v0 = 0, v1 = 0, v2 = 0, v3 = 0;
    if (base + 0 < N) v0 = deg[base + 0];
    if (base + 1 < N) v1 = deg[base + 1];
    if (base + 2 < N) v2 = deg[base + 2];
    if (base + 3 < N) v3 = deg[base + 3];
    int tot = v0 + v1 + v2 + v3;
    tsum[t] = tot;
    __syncthreads();
    for (int off = 1; off < 256; off <<= 1) {
        int y = (t >= off) ? tsum[t - off] : 0;
        __syncthreads();
        tsum[t] += y;
        __syncthreads();
    }
    int excl = tsum[t] - tot;
    if (base + 0 < N) rp[base + 0] = excl;
    if (base + 1 < N) rp[base + 1] = excl + v0;
    if (base + 2 < N) rp[base + 2] = excl + v0 + v1;
    if (base + 3 < N) rp[base + 3] = excl + v0 + v1 + v2;
    if (t == 255) bsum[blockIdx.x] = tsum[255];
}

__global__ void scan2(int* __restrict__ bsum, int NB) {
    __shared__ int s[256];
    int t = threadIdx.x;
    int v = (t < NB) ? bsum[t] : 0;
    s[t] = v;
    __syncthreads();
    for (int off = 1; off < 256; off <<= 1) {
        int y = (t >= off) ? s[t - off] : 0;
        __syncthreads();
        s[t] += y;
        __syncthreads();
    }
    if (t < NB) bsum[t] = s[t] - v;   // exclusive
}

__global__ void scan3(int* __restrict__ rp, const int* __restrict__ bsum,
                      int* __restrict__ cur, int N, int E) {
    int i = blockIdx.x * 256 + threadIdx.x;
    if (i < N) {
        int v = rp[i] + bsum[i >> 10];
        rp[i] = v;
        cur[i] = v;
    }
    if (i == 0) rp[N] = E;
}

__global__ void scatter_all(const int* __restrict__ gg_src, const int* __restrict__ gg_dst,
                            const int* __restrict__ dg_src, const int* __restrict__ dg_dst,
                            int* __restrict__ cur, int* __restrict__ col) {
    int e = blockIdx.x * 256 + threadIdx.x;
    int s, dn;
    if (e < EGG) { s = gg_src[e]; dn = gg_dst[e]; }
    else if (e < EALL) { s = dg_src[e - EGG]; dn = NG + dg_dst[e - EGG]; }
    else return;
    int pos = atomicAdd(&cur[dn], 1);
    col[pos] = s;
}

// ---------------- fused GAT gather v2: one wave per dst node ----------------
__launch_bounds__(256)
__global__ void gat_gather(const int* __restrict__ rp, const int* __restrict__ col,
                           const float* __restrict__ a_s, const float* __restrict__ a_d,
                           const float* __restrict__ xsrc, float* __restrict__ outb,
                           int ndst) {
    int wid = (blockIdx.x * 256 + threadIdx.x) >> 6;
    int l = threadIdx.x & 63;
    if (wid >= ndst) return;
    int d = wid;
    int base = rp[d];
    int deg = rp[d + 1] - base;

    int hl = l & 7;          // head for phase-1 / alpha layout
    int g  = l >> 3;         // edge subgroup
    float adl = a_d[d * 8 + hl];
    // phase 1: online (m, ssum) per head
    float m = -1e30f, ssum = 0.f;
    for (int c0 = 0; c0 < deg; c0 += 64) {
        int myi = c0 + l;
        int colreg = (myi < deg) ? col[base + myi] : 0;
        int lim = min(deg - c0, 64);
        for (int t = g; t < lim; t += 8) {
            int s = __shfl(colreg, t);
            float a = a_s[s * 8 + hl] + adl;
            a = a > 0.f ? a : 0.2f * a;
            float nm = fmaxf(m, a);
            ssum = ssum * __expf(m - nm) + __expf(a - nm);
            m = nm;
        }
    }
    for (int off = 8; off < 64; off <<= 1) {
        float m2 = __shfl_xor(m, off);
        float s2 = __shfl_xor(ssum, off);
        float nm = fmaxf(m, m2);
        ssum = ssum * __expf(m - nm) + s2 * __expf(m2 - nm);
        m = nm;
    }
    float rsc = 1.f / (ssum + 1e-16f);   // lane l holds (m, rsc) for head l&7

    // phase 2: lanes 0-31 = even edge of pair, 32-63 = odd; lane covers cols 4cl..4cl+3
    int half = l >> 5;
    int cl = l & 31;
    int hc = cl >> 2;                     // head of my col block
    uint32_t colbyte = (uint32_t)cl << 4; // 16 B per col block
    float4 acc = {0.f, 0.f, 0.f, 0.f};
    for (int c0 = 0; c0 < deg; c0 += 64) {
        int myi = c0 + l;
        int colreg = (myi < deg) ? col[base + myi] : 0;
        int lim = min(deg - c0, 64);
        for (int j8 = 0; j8 < lim; j8 += 8) {
            // batch: lane l computes alpha for (edge j8+(l>>3), head l&7)
            float alpha;
            {
                int s = __shfl(colreg, j8 + g);
                float a = a_s[s * 8 + hl] + adl;
                a = a > 0.f ? a : 0.2f * a;
                alpha = __expf(a - m) * rsc;
            }
            int jlim = min(lim - j8, 8);
            int jj = 0;
            for (; jj + 2 <= jlim; jj += 2) {
                int jrel = jj + half;
                int s = __shfl(colreg, j8 + jrel);
                float al = __shfl(alpha, (jrel << 3) + hc);
                const float4 xv = *(const float4*)((const char*)xsrc +
                                    (((size_t)(uint32_t)s << 9) + colbyte));
                acc.x += al * xv.x; acc.y += al * xv.y;
                acc.z += al * xv.z; acc.w += al * xv.w;
            }
            if (jj < jlim) {   // odd tail: single edge on lower half
                int s = __shfl(colreg, j8 + jj);
                float al = __shfl(alpha, (jj << 3) + hc);
                if (half == 0) {
                    const float4 xv = *(const float4*)((const char*)xsrc +
                                        (((size_t)(uint32_t)s << 9) + colbyte));
                    acc.x += al * xv.x; acc.y += al * xv.y;
                    acc.z += al * xv.z; acc.w += al * xv.w;
                }
            }
        }
    }
    acc.x += __shfl_xor(acc.x, 32);
    acc.y += __shfl_xor(acc.y, 32);
    acc.z += __shfl_xor(acc.z, 32);
    acc.w += __shfl_xor(acc.w, 32);
    if (half == 0)
        *(float4*)&outb[(size_t)d * 128 + cl * 4] = acc;
}

// ---------------- kmean: both metapaths; kpart[0:128]=gg col-sums, [128:256]=dg ----------------
__launch_bounds__(256)
__global__ void kmean_gemm2(const float* __restrict__ out_gg, const float* __restrict__ out_dg,
                            const float* __restrict__ W, const float* __restrict__ bias,
                            float* __restrict__ kpart) {
    __shared__ float Ws[128 * 128];
    __shared__ float rows_s[32][128];
    for (int idx = threadIdx.x; idx < 128 * 128; idx += 256) {
        int i = idx >> 7, j = idx & 127;
        Ws[i * 128 + j] = W[j * 128 + i];
    }
    int g = threadIdx.x >> 5;
    int l = threadIdx.x & 31;
    int g4 = g * 4;
    float4 bvec = *(const float4*)&bias[l * 4];
    float4 accA = {0,0,0,0}, accB = {0,0,0,0};
    __syncthreads();
    for (int base = blockIdx.x * 32; base < NALL; base += gridDim.x * 32) {
        bool isA = base < NG;     // NG % 32 == 0: no straddle
        #pragma unroll
        for (int k = 0; k < 4; k++) {
            int n = base + g4 + k;
            const float* src = isA ? &out_gg[(size_t)n * 128] : &out_dg[(size_t)(n - NG) * 128];
            float4 v = *(const float4*)&src[l * 4];
            v.x = fmaxf(v.x, 0.f); v.y = fmaxf(v.y, 0.f);
            v.z = fmaxf(v.z, 0.f); v.w = fmaxf(v.w, 0.f);
            *(float4*)&rows_s[g4 + k][l * 4] = v;
        }
        __syncthreads();
        float4 acc0 = bvec, acc1 = bvec, acc2 = bvec, acc3 = bvec;
        #pragma unroll 4
        for (int i = 0; i < 128; i++) {
            float4 w = *(const float4*)&Ws[i * 128 + l * 4];
            float x0 = rows_s[g4 + 0][i];
            float x1 = rows_s[g4 + 1][i];
            float x2 = rows_s[g4 + 2][i];
            float x3 = rows_s[g4 + 3][i];
            acc0.x += x0 * w.x; acc0.y += x0 * w.y; acc0.z += x0 * w.z; acc0.w += x0 * w.w;
            acc1.x += x1 * w.x; acc1.y += x1 * w.y; acc1.z += x1 * w.z; acc1.w += x1 * w.w;
            acc2.x += x2 * w.x; acc2.y += x2 * w.y; acc2.z += x2 * w.z; acc2.w += x2 * w.w;
            acc3.x += x3 * w.x; acc3.y += x3 * w.y; acc3.z += x3 * w.z; acc3.w += x3 * w.w;
        }
        float4* accp = isA ? &accA : &accB;
        accp->x += fast_tanh(acc0.x) + fast_tanh(acc1.x) + fast_tanh(acc2.x) + fast_tanh(acc3.x);
        accp->y += fast_tanh(acc0.y) + fast_tanh(acc1.y) + fast_tanh(acc2.y) + fast_tanh(acc3.y);
        accp->z += fast_tanh(acc0.z) + fast_tanh(acc1.z) + fast_tanh(acc2.z) + fast_tanh(acc3.z);
        accp->w += fast_tanh(acc0.w) + fast_tanh(acc1.w) + fast_tanh(acc2.w) + fast_tanh(acc3.w);
        __syncthreads();
    }
    // block-reduce accA then accB (reuse rows_s)
    *(float4*)&rows_s[g][l * 4] = accA;
    __syncthreads();
    if (threadIdx.x < 128) {
        float s = 0.f;
        #pragma unroll
        for (int gg2 = 0; gg2 < 8; gg2++) s += rows_s[gg2][threadIdx.x];
        atomicAdd(&kpart[threadIdx.x], s);
    }
    __syncthreads();
    *(float4*)&rows_s[g][l * 4] = accB;
    __syncthreads();
    if (threadIdx.x < 128) {
        float s = 0.f;
        #pragma unroll
        for (int gg2 = 0; gg2 < 8; gg2++) s += rows_s[gg2][threadIdx.x];
        atomicAdd(&kpart[128 + threadIdx.x], s);
    }
}

// ---------------- semantic softmax (2 scores) ----------------
__global__ void score_attn(const float* __restrict__ kpart, const float* __restrict__ q,
                           float* __restrict__ attn) {
    __shared__ float r0[128], r1[128];
    int t = threadIdx.x;
    r0[t] = q[t] * kpart[t];
    r1[t] = q[t] * kpart[128 + t];
    __syncthreads();
    for (int s = 64; s > 0; s >>= 1) {
        if (t < s) { r0[t] += r0[t + s]; r1[t] += r1[t + s]; }
        __syncthreads();
    }
    if (t == 0) {
        float s0 = r0[0] / (float)NG, s1 = r1[0] / (float)NG;
        float mx = fmaxf(s0, s1);
        float e0 = expf(s0 - mx), e1 = expf(s1 - mx);
        attn[0] = e0 / (e0 + e1);
        attn[1] = e1 / (e0 + e1);
    }
}

// ---------------- fused combine + final linear: one wave per node ----------------
__launch_bounds__(256)
__global__ void final_lin(const float* __restrict__ gg, const float* __restrict__ dgb,
                          const float* __restrict__ attn, const float* __restrict__ lin_w,
                          const float* __restrict__ lin_b, float* __restrict__ outp) {
    int wid = (blockIdx.x * 256 + threadIdx.x) >> 6;
    int l = threadIdx.x & 63;
    if (wid >= NG) return;
    float a0 = attn[0], a1 = attn[1];
    float2 gv = *(const float2*)&gg[(size_t)wid * 128 + l * 2];
    float2 dv = *(const float2*)&dgb[(size_t)wid * 128 + l * 2];
    float fx = a0 * fmaxf(gv.x, 0.f) + a1 * fmaxf(dv.x, 0.f);
    float fy = a0 * fmaxf(gv.y, 0.f) + a1 * fmaxf(dv.y, 0.f);
    float2 w0 = *(const float2*)&lin_w[l * 2];
    float2 w1 = *(const float2*)&lin_w[128 + l * 2];
    float p0 = fx * w0.x + fy * w0.y;
    float p1 = fx * w1.x + fy * w1.y;
    for (int off = 32; off > 0; off >>= 1) {
        p0 += __shfl_down(p0, off);
        p1 += __shfl_down(p1, off);
    }
    if (l == 0) {
        float2 o;
        o.x = p0 + lin_b[0];
        o.y = p1 + lin_b[1];
        *(float2*)&outp[wid * 2] = o;
    }
}

extern "C" void kernel_launch(void* const* d_in, const int* in_sizes, int n_in,
                              void* d_out, int out_size, void* d_ws, size_t ws_size,
                              hipStream_t stream) {
    const float* x_gene    = (const float*)d_in[0];
    const float* x_disease = (const float*)d_in[1];
    const int*   edge_gg   = (const int*)d_in[2];
    const int*   edge_dg   = (const int*)d_in[3];
    const float* pg_w      = (const float*)d_in[4];
    const float* pg_b      = (const float*)d_in[5];
    const float* pd_w      = (const float*)d_in[6];
    const float* pd_b      = (const float*)d_in[7];
    const float* att_src_gg= (const float*)d_in[8];
    const float* att_dst_gg= (const float*)d_in[9];
    const float* att_src_dg= (const float*)d_in[10];
    const float* att_dst_dg= (const float*)d_in[11];
    const float* k_lin_w   = (const float*)d_in[12];
    const float* k_lin_b   = (const float*)d_in[13];
    const float* q         = (const float*)d_in[14];
    const float* lin_w     = (const float*)d_in[15];
    const float* lin_b     = (const float*)d_in[16];
    float* out = (float*)d_out;
    float* ws  = (float*)d_ws;

    float* out_gg = ws + OFF_OUT_GG;
    float* out_dg = ws + OFF_OUT_DG;
    float* xg     = ws + OFF_XG;
    float* xd     = ws + OFF_XD;
    float* a_src_gg = ws + OFF_ASG;
    float* a_dst_gg = ws + OFF_ADG;
    float* a_dst_dg = ws + OFF_ADD;
    float* a_src_dg = ws + OFF_ASD;
    float* kpart  = ws + OFF_KPART;
    float* attn   = ws + OFF_ATTN;
    int* deg = (int*)(ws + OFF_DEG);
    int* rp  = (int*)(ws + OFF_RP);
    int* cur = (int*)(ws + OFF_CUR);
    int* bsum = (int*)(ws + OFF_BSUM);
    int* col = (int*)(ws + OFF_COL);

    const int* gg_src = edge_gg;
    const int* gg_dst = edge_gg + EGG;
    const int* dg_src = edge_dg;
    const int* dg_dst = edge_dg + EDG;

    // 1. zero kpart + degree arrays
    hipLaunchKernelGGL(init_zero_k, dim3((ZERO_CNT + 255) / 256), dim3(256), 0, stream,
                       ws + ZERO_BASE, ZERO_CNT);
    // 2. projections with fused att-logit epilogue
    hipLaunchKernelGGL(proj_gemm_fused, dim3(512), dim3(256), 0, stream,
                       x_gene, pg_w, pg_b, xg, NG, 3,
                       att_src_gg, att_dst_gg, att_dst_dg, a_src_gg, a_dst_gg, a_dst_dg);
    hipLaunchKernelGGL(proj_gemm_fused, dim3(512), dim3(256), 0, stream,
                       x_disease, pd_w, pd_b, xd, ND, 1,
                       att_src_dg, (const float*)nullptr, (const float*)nullptr,
                       a_src_dg, (float*)nullptr, (float*)nullptr);
    // 3. merged CSR build (gg nodes 0..NG-1, dg nodes NG..2NG-1)
    hipLaunchKernelGGL(count_all, dim3((EALL + 255) / 256), dim3(256), 0, stream,
                       gg_dst, dg_dst, deg);
    hipLaunchKernelGGL(scan1, dim3((NALL + 1023) / 1024), dim3(256), 0, stream, deg, rp, bsum, NALL);
    hipLaunchKernelGGL(scan2, dim3(1), dim3(256), 0, stream, bsum, (NALL + 1023) / 1024);
    hipLaunchKernelGGL(scan3, dim3((NALL + 255) / 256), dim3(256), 0, stream, rp, bsum, cur, NALL, EALL);
    hipLaunchKernelGGL(scatter_all, dim3((EALL + 255) / 256), dim3(256), 0, stream,
                       gg_src, gg_dst, dg_src, dg_dst, cur, col);
    // 4. fused gathers
    hipLaunchKernelGGL(gat_gather, dim3((NG + 3) / 4), dim3(256), 0, stream,
                       rp, col, a_src_gg, a_dst_gg, xg, out_gg, NG);
    hipLaunchKernelGGL(gat_gather, dim3((NG + 3) / 4), dim3(256), 0, stream,
                       rp + NG, col, a_src_dg, a_dst_dg, xd, out_dg, NG);
    // 5. semantic attention
    hipLaunchKernelGGL(kmean_gemm2, dim3(512), dim3(256), 0, stream,
                       out_gg, out_dg, k_lin_w, k_lin_b, kpart);
    hipLaunchKernelGGL(score_attn, dim3(1), dim3(128), 0, stream, kpart, q, attn);
    // 6. fused combine + final linear
    hipLaunchKernelGGL(final_lin, dim3((NG + 3) / 4), dim3(256), 0, stream,
                       out_gg, out_dg, attn, lin_w, lin_b, out);
}

// Round 4
// 712.317 us; speedup vs baseline: 2.5266x; 1.1398x over previous
//
#include <hip/hip_runtime.h>
#include <math.h>

#define NG 100000
#define ND 50000
#define EGG 1600000
#define EDG 800000
#define EALL (EGG + EDG)
#define NALL (NG + NG)
#define HID 128
#define NH 8

// bucket sort params
#define SHIFT 11
#define BDSTS (1 << SHIFT)          // 2048 dsts per bucket
#define NBUK  ((NALL + BDSTS - 1) / BDSTS)   // 98
#define S1_CH 6144                  // edges per bucket_scatter block

// ---------------- workspace layout (4-byte element offsets) ----------------
#define OFF_OUT_GG 0UL          // 12,800,000  (colPacked overlays this until gat_gather)
#define OFF_OUT_DG 12800000UL   // 12,800,000
#define OFF_XG     25600000UL   // 12,800,000
#define OFF_XD     38400000UL   //  6,400,000
#define OFF_ASG    44800000UL   //    800,000  a_src_gg [NG,8]
#define OFF_ADG    45600000UL   //    800,000  a_dst_gg [NG,8]
#define OFF_ADD    46400000UL   //    800,000  a_dst_dg [NG,8]
#define OFF_ASD    47200000UL   //    400,000  a_src_dg [ND,8]
#define OFF_KPART  47600000UL   //        256  (zero-init)
#define OFF_DEG    47600256UL   //    200,000  (zero-init) [gg | dg]
#define ZERO_BASE  OFF_KPART
#define ZERO_CNT   200256
#define OFF_ATTN   47800256UL   //          2 (+pad)
#define OFF_RP     47800272UL   //    200,001 (+pad to 200,008)
#define OFF_BCUR   48000280UL   //        256
#define OFF_BSUM   48200280UL   //        256
#define OFF_COL    48200536UL   //  2,400,000
// end: 50,600,536 elems = 202.4 MB

__device__ __forceinline__ float fast_tanh(float x) {
    x = fminf(fmaxf(x, -15.f), 15.f);
    float t = __expf(2.f * x);
    return (t - 1.f) / (t + 1.f);
}

// ---------------- init ----------------
__global__ void init_zero_k(float* __restrict__ p, int n) {
    int i = blockIdx.x * 256 + threadIdx.x;
    if (i < n) p[i] = 0.f;
}

// ---------------- projection GEMM + fused attention-logit epilogue ----------------
__launch_bounds__(256)
__global__ void proj_gemm_fused(const float* __restrict__ x, const float* __restrict__ W,
                                const float* __restrict__ bias, float* __restrict__ out, int N,
                                int natt,
                                const float* __restrict__ att0, const float* __restrict__ att1,
                                const float* __restrict__ att2,
                                float* __restrict__ o0, float* __restrict__ o1,
                                float* __restrict__ o2) {
    __shared__ float Ws[128 * 128];       // Ws[i*128 + j] = W[j*128 + i]
    __shared__ float rows_s[32][128];
    for (int idx = threadIdx.x; idx < 128 * 128; idx += 256) {
        int i = idx >> 7, j = idx & 127;
        Ws[i * 128 + j] = W[j * 128 + i];
    }
    int g = threadIdx.x >> 5;   // group 0..7, 4 rows each
    int l = threadIdx.x & 31;
    int g4 = g * 4;
    float4 bvec = *(const float4*)&bias[l * 4];
    float4 at0 = {0,0,0,0}, at1 = {0,0,0,0}, at2 = {0,0,0,0};
    if (natt > 0) at0 = *(const float4*)&att0[l * 4];
    if (natt > 1) at1 = *(const float4*)&att1[l * 4];
    if (natt > 2) at2 = *(const float4*)&att2[l * 4];
    __syncthreads();
    for (int base = blockIdx.x * 32; base < N; base += gridDim.x * 32) {
        int r0 = base + g4;
        #pragma unroll
        for (int k = 0; k < 4; k++) {
            int n = r0 + k;
            if (n < N)
                *(float4*)&rows_s[g4 + k][l * 4] = *(const float4*)&x[(size_t)n * 128 + l * 4];
        }
        __syncthreads();
        float4 acc0 = bvec, acc1 = bvec, acc2 = bvec, acc3 = bvec;
        #pragma unroll 4
        for (int i = 0; i < 128; i++) {
            float4 w = *(const float4*)&Ws[i * 128 + l * 4];
            float x0 = rows_s[g4 + 0][i];
            float x1 = rows_s[g4 + 1][i];
            float x2 = rows_s[g4 + 2][i];
            float x3 = rows_s[g4 + 3][i];
            acc0.x += x0 * w.x; acc0.y += x0 * w.y; acc0.z += x0 * w.z; acc0.w += x0 * w.w;
            acc1.x += x1 * w.x; acc1.y += x1 * w.y; acc1.z += x1 * w.z; acc1.w += x1 * w.w;
            acc2.x += x2 * w.x; acc2.y += x2 * w.y; acc2.z += x2 * w.z; acc2.w += x2 * w.w;
            acc3.x += x3 * w.x; acc3.y += x3 * w.y; acc3.z += x3 * w.z; acc3.w += x3 * w.w;
        }
        #define ROW_EPI(ACC, KK) do { \
            int n = r0 + KK; \
            if (n < N) { \
                *(float4*)&out[(size_t)n * 128 + l * 4] = ACC; \
                if (natt > 0) { \
                    float p = ACC.x*at0.x + ACC.y*at0.y + ACC.z*at0.z + ACC.w*at0.w; \
                    p += __shfl_xor(p, 1); p += __shfl_xor(p, 2); \
                    if ((l & 3) == 0) o0[n * 8 + (l >> 2)] = p; } \
                if (natt > 1) { \
                    float p = ACC.x*at1.x + ACC.y*at1.y + ACC.z*at1.z + ACC.w*at1.w; \
                    p += __shfl_xor(p, 1); p += __shfl_xor(p, 2); \
                    if ((l & 3) == 0) o1[n * 8 + (l >> 2)] = p; } \
                if (natt > 2) { \
                    float p = ACC.x*at2.x + ACC.y*at2.y + ACC.z*at2.z + ACC.w*at2.w; \
                    p += __shfl_xor(p, 1); p += __shfl_xor(p, 2); \
                    if ((l & 3) == 0) o2[n * 8 + (l >> 2)] = p; } \
            } } while (0)
        ROW_EPI(acc0, 0); ROW_EPI(acc1, 1); ROW_EPI(acc2, 2); ROW_EPI(acc3, 3);
        #undef ROW_EPI
        __syncthreads();
    }
}

// ---------------- CSR build (gg nodes [0,NG), dg nodes [NG,2NG)) ----------------
__global__ void count_all(const int* __restrict__ gg_dst, const int* __restrict__ dg_dst,
                          int* __restrict__ deg) {
    int e = blockIdx.x * 256 + threadIdx.x;
    if (e < EGG) atomicAdd(&deg[gg_dst[e]], 1);
    else if (e < EALL) atomicAdd(&deg[NG + dg_dst[e - EGG]], 1);
}

__global__ void scan1(const int* __restrict__ deg, int* __restrict__ rp,
                      int* __restrict__ bsum, int N) {
    __shared__ int tsum[256];
    int t = threadIdx.x;
    int base = blockIdx.x * 1024 + t * 4;
    int v0 = 0, v1 = 0, v2 = 0, v3 = 0;
    if (base + 0 < N) v0 = deg[base + 0];
    if (base + 1 < N) v1 = deg[base + 1];
    if (base + 2 < N) v2 = deg[base + 2];
    if (base + 3 < N) v3 = deg[base + 3];
    int tot = v0 + v1 + v2 + v3;
    tsum[t] = tot;
    __syncthreads();
    for (int off = 1; off < 256; off <<= 1) {
        int y = (t >= off) ? tsum[t - off] : 0;
        __syncthreads();
        tsum[t] += y;
        __syncthreads();
    }
    int excl = tsum[t] - tot;
    if (base + 0 < N) rp[base + 0] = excl;
    if (base + 1 < N) rp[base + 1] = excl + v0;
    if (base + 2 < N) rp[base + 2] = excl + v0 + v1;
    if (base + 3 < N) rp[base + 3] = excl + v0 + v1 + v2;
    if (t == 255) bsum[blockIdx.x] = tsum[255];
}

__global__ void scan2(int* __restrict__ bsum, int NB) {
    __shared__ int s[256];
    int t = threadIdx.x;
    int v = (t < NB) ? bsum[t] : 0;
    s[t] = v;
    __syncthreads();
    for (int off = 1; off < 256; off <<= 1) {
        int y = (t >= off) ? s[t - off] : 0;
        __syncthreads();
        s[t] += y;
        __syncthreads();
    }
    if (t < NB) bsum[t] = s[t] - v;   // exclusive
}

__global__ void scan3(int* __restrict__ rp, const int* __restrict__ bsum,
                      int* __restrict__ bcur, int N, int E) {
    int i = blockIdx.x * 256 + threadIdx.x;
    if (i < N) {
        int v = rp[i] + bsum[i >> 10];
        rp[i] = v;
        if ((i & (BDSTS - 1)) == 0) bcur[i >> SHIFT] = v;   // bucket base cursor
    }
    if (i == 0) rp[N] = E;
}

// ---------------- S1: LDS-staged bucket scatter (coalesced writes) ----------------
__launch_bounds__(256)
__global__ void bucket_scatter(const int* __restrict__ gg_src, const int* __restrict__ gg_dst,
                               const int* __restrict__ dg_src, const int* __restrict__ dg_dst,
                               int* __restrict__ bcur, unsigned int* __restrict__ colPacked) {
    __shared__ int cnt[256], scanE[256], gbase[256], cursor[256];
    __shared__ unsigned int sorted[S1_CH];
    __shared__ unsigned char bof[S1_CH];
    int t = threadIdx.x;
    cnt[t] = 0;
    __syncthreads();
    int base = blockIdx.x * S1_CH;
    // A1: bucket histogram
    for (int k = 0; k < S1_CH; k += 256) {
        int e = base + k + t;
        if (e < EALL) {
            int dn = (e < EGG) ? gg_dst[e] : (NG + dg_dst[e - EGG]);
            atomicAdd(&cnt[dn >> SHIFT], 1);
        }
    }
    __syncthreads();
    // A2: exclusive scan over 256 counters
    int v = cnt[t];
    int incl = v;
    __shared__ int ss[256];
    ss[t] = incl;
    __syncthreads();
    for (int off = 1; off < 256; off <<= 1) {
        int y = (t >= off) ? ss[t - off] : 0;
        __syncthreads();
        ss[t] += y;
        __syncthreads();
    }
    scanE[t] = ss[t] - v;
    cursor[t] = ss[t] - v;
    // A2b: reserve global space (one atomic per non-empty bucket)
    if (t < NBUK && v > 0) gbase[t] = atomicAdd(&bcur[t], v);
    __syncthreads();
    // A3: place entries into locally-sorted LDS
    for (int k = 0; k < S1_CH; k += 256) {
        int e = base + k + t;
        if (e < EALL) {
            int s, dn;
            if (e < EGG) { s = gg_src[e]; dn = gg_dst[e]; }
            else         { s = dg_src[e - EGG]; dn = NG + dg_dst[e - EGG]; }
            int b = dn >> SHIFT;
            int slot = atomicAdd(&cursor[b], 1);
            sorted[slot] = ((unsigned int)s << SHIFT) | (unsigned int)(dn & (BDSTS - 1));
            bof[slot] = (unsigned char)b;
        }
    }
    __syncthreads();
    // A5: coalesced flush (per bucket: contiguous run at gbase[b])
    int total = ss[255];
    for (int f = t; f < total; f += 256) {
        int b = bof[f];
        colPacked[gbase[b] + (f - scanE[b])] = sorted[f];
    }
}

// ---------------- S2: bucket-local counting sort into exact CSR positions ----------------
__launch_bounds__(256)
__global__ void bucket_sort(const unsigned int* __restrict__ colPacked,
                            const int* __restrict__ rp, int* __restrict__ col) {
    __shared__ int lcur[BDSTS];
    int b = blockIdx.x;
    int d0 = b << SHIFT;
    int dEnd = min(d0 + BDSTS, NALL);
    int nd = dEnd - d0;
    for (int i = threadIdx.x; i < nd; i += 256) lcur[i] = rp[d0 + i];
    __syncthreads();
    int ebase = rp[d0];
    int eend  = rp[dEnd];
    for (int i = ebase + threadIdx.x; i < eend; i += 256) {
        unsigned int p = colPacked[i];
        int dlow = (int)(p & (BDSTS - 1));
        int s    = (int)(p >> SHIFT);
        int pos = atomicAdd(&lcur[dlow], 1);
        col[pos] = s;   // random only within this bucket's ~100 KB window (L2-resident)
    }
}

// ---------------- fused GAT gather v2: one wave per dst node ----------------
__launch_bounds__(256)
__global__ void gat_gather(const int* __restrict__ rp, const int* __restrict__ col,
                           const float* __restrict__ a_s, const float* __restrict__ a_d,
                           const float* __restrict__ xsrc, float* __restrict__ outb,
                           int ndst) {
    int wid = (blockIdx.x * 256 + threadIdx.x) >> 6;
    int l = threadIdx.x & 63;
    if (wid >= ndst) return;
    int d = wid;
    int base = rp[d];
    int deg = rp[d + 1] - base;

    int hl = l & 7;
    int g  = l >> 3;
    float adl = a_d[d * 8 + hl];
    float m = -1e30f, ssum = 0.f;
    for (int c0 = 0; c0 < deg; c0 += 64) {
        int myi = c0 + l;
        int colreg = (myi < deg) ? col[base + myi] : 0;
        int lim = min(deg - c0, 64);
        for (int t = g; t < lim; t += 8) {
            int s = __shfl(colreg, t);
            float a = a_s[s * 8 + hl] + adl;
            a = a > 0.f ? a : 0.2f * a;
            float nm = fmaxf(m, a);
            ssum = ssum * __expf(m - nm) + __expf(a - nm);
            m = nm;
        }
    }
    for (int off = 8; off < 64; off <<= 1) {
        float m2 = __shfl_xor(m, off);
        float s2 = __shfl_xor(ssum, off);
        float nm = fmaxf(m, m2);
        ssum = ssum * __expf(m - nm) + s2 * __expf(m2 - nm);
        m = nm;
    }
    float rsc = 1.f / (ssum + 1e-16f);

    int half = l >> 5;
    int cl = l & 31;
    int hc = cl >> 2;
    uint32_t colbyte = (uint32_t)cl << 4;
    float4 acc = {0.f, 0.f, 0.f, 0.f};
    for (int c0 = 0; c0 < deg; c0 += 64) {
        int myi = c0 + l;
        int colreg = (myi < deg) ? col[base + myi] : 0;
        int lim = min(deg - c0, 64);
        for (int j8 = 0; j8 < lim; j8 += 8) {
            float alpha;
            {
                int s = __shfl(colreg, j8 + g);
                float a = a_s[s * 8 + hl] + adl;
                a = a > 0.f ? a : 0.2f * a;
                alpha = __expf(a - m) * rsc;
            }
            int jlim = min(lim - j8, 8);
            int jj = 0;
            for (; jj + 2 <= jlim; jj += 2) {
                int jrel = jj + half;
                int s = __shfl(colreg, j8 + jrel);
                float al = __shfl(alpha, (jrel << 3) + hc);
                const float4 xv = *(const float4*)((const char*)xsrc +
                                    (((size_t)(uint32_t)s << 9) + colbyte));
                acc.x += al * xv.x; acc.y += al * xv.y;
                acc.z += al * xv.z; acc.w += al * xv.w;
            }
            if (jj < jlim) {
                int s = __shfl(colreg, j8 + jj);
                float al = __shfl(alpha, (jj << 3) + hc);
                if (half == 0) {
                    const float4 xv = *(const float4*)((const char*)xsrc +
                                        (((size_t)(uint32_t)s << 9) + colbyte));
                    acc.x += al * xv.x; acc.y += al * xv.y;
                    acc.z += al * xv.z; acc.w += al * xv.w;
                }
            }
        }
    }
    acc.x += __shfl_xor(acc.x, 32);
    acc.y += __shfl_xor(acc.y, 32);
    acc.z += __shfl_xor(acc.z, 32);
    acc.w += __shfl_xor(acc.w, 32);
    if (half == 0)
        *(float4*)&outb[(size_t)d * 128 + cl * 4] = acc;
}

// ---------------- kmean: both metapaths ----------------
__launch_bounds__(256)
__global__ void kmean_gemm2(const float* __restrict__ out_gg, const float* __restrict__ out_dg,
                            const float* __restrict__ W, const float* __restrict__ bias,
                            float* __restrict__ kpart) {
    __shared__ float Ws[128 * 128];
    __shared__ float rows_s[32][128];
    for (int idx = threadIdx.x; idx < 128 * 128; idx += 256) {
        int i = idx >> 7, j = idx & 127;
        Ws[i * 128 + j] = W[j * 128 + i];
    }
    int g = threadIdx.x >> 5;
    int l = threadIdx.x & 31;
    int g4 = g * 4;
    float4 bvec = *(const float4*)&bias[l * 4];
    float4 accA = {0,0,0,0}, accB = {0,0,0,0};
    __syncthreads();
    for (int base = blockIdx.x * 32; base < NALL; base += gridDim.x * 32) {
        bool isA = base < NG;
        #pragma unroll
        for (int k = 0; k < 4; k++) {
            int n = base + g4 + k;
            const float* src = isA ? &out_gg[(size_t)n * 128] : &out_dg[(size_t)(n - NG) * 128];
            float4 v = *(const float4*)&src[l * 4];
            v.x = fmaxf(v.x, 0.f); v.y = fmaxf(v.y, 0.f);
            v.z = fmaxf(v.z, 0.f); v.w = fmaxf(v.w, 0.f);
            *(float4*)&rows_s[g4 + k][l * 4] = v;
        }
        __syncthreads();
        float4 acc0 = bvec, acc1 = bvec, acc2 = bvec, acc3 = bvec;
        #pragma unroll 4
        for (int i = 0; i < 128; i++) {
            float4 w = *(const float4*)&Ws[i * 128 + l * 4];
            float x0 = rows_s[g4 + 0][i];
            float x1 = rows_s[g4 + 1][i];
            float x2 = rows_s[g4 + 2][i];
            float x3 = rows_s[g4 + 3][i];
            acc0.x += x0 * w.x; acc0.y += x0 * w.y; acc0.z += x0 * w.z; acc0.w += x0 * w.w;
            acc1.x += x1 * w.x; acc1.y += x1 * w.y; acc1.z += x1 * w.z; acc1.w += x1 * w.w;
            acc2.x += x2 * w.x; acc2.y += x2 * w.y; acc2.z += x2 * w.z; acc2.w += x2 * w.w;
            acc3.x += x3 * w.x; acc3.y += x3 * w.y; acc3.z += x3 * w.z; acc3.w += x3 * w.w;
        }
        float4* accp = isA ? &accA : &accB;
        accp->x += fast_tanh(acc0.x) + fast_tanh(acc1.x) + fast_tanh(acc2.x) + fast_tanh(acc3.x);
        accp->y += fast_tanh(acc0.y) + fast_tanh(acc1.y) + fast_tanh(acc2.y) + fast_tanh(acc3.y);
        accp->z += fast_tanh(acc0.z) + fast_tanh(acc1.z) + fast_tanh(acc2.z) + fast_tanh(acc3.z);
        accp->w += fast_tanh(acc0.w) + fast_tanh(acc1.w) + fast_tanh(acc2.w) + fast_tanh(acc3.w);
        __syncthreads();
    }
    *(float4*)&rows_s[g][l * 4] = accA;
    __syncthreads();
    if (threadIdx.x < 128) {
        float s = 0.f;
        #pragma unroll
        for (int gg2 = 0; gg2 < 8; gg2++) s += rows_s[gg2][threadIdx.x];
        atomicAdd(&kpart[threadIdx.x], s);
    }
    __syncthreads();
    *(float4*)&rows_s[g][l * 4] = accB;
    __syncthreads();
    if (threadIdx.x < 128) {
        float s = 0.f;
        #pragma unroll
        for (int gg2 = 0; gg2 < 8; gg2++) s += rows_s[gg2][threadIdx.x];
        atomicAdd(&kpart[128 + threadIdx.x], s);
    }
}

// ---------------- semantic softmax (2 scores) ----------------
__global__ void score_attn(const float* __restrict__ kpart, const float* __restrict__ q,
                           float* __restrict__ attn) {
    __shared__ float r0[128], r1[128];
    int t = threadIdx.x;
    r0[t] = q[t] * kpart[t];
    r1[t] = q[t] * kpart[128 + t];
    __syncthreads();
    for (int s = 64; s > 0; s >>= 1) {
        if (t < s) { r0[t] += r0[t + s]; r1[t] += r1[t + s]; }
        __syncthreads();
    }
    if (t == 0) {
        float s0 = r0[0] / (float)NG, s1 = r1[0] / (float)NG;
        float mx = fmaxf(s0, s1);
        float e0 = expf(s0 - mx), e1 = expf(s1 - mx);
        attn[0] = e0 / (e0 + e1);
        attn[1] = e1 / (e0 + e1);
    }
}

// ---------------- fused combine + final linear: one wave per node ----------------
__launch_bounds__(256)
__global__ void final_lin(const float* __restrict__ gg, const float* __restrict__ dgb,
                          const float* __restrict__ attn, const float* __restrict__ lin_w,
                          const float* __restrict__ lin_b, float* __restrict__ outp) {
    int wid = (blockIdx.x * 256 + threadIdx.x) >> 6;
    int l = threadIdx.x & 63;
    if (wid >= NG) return;
    float a0 = attn[0], a1 = attn[1];
    float2 gv = *(const float2*)&gg[(size_t)wid * 128 + l * 2];
    float2 dv = *(const float2*)&dgb[(size_t)wid * 128 + l * 2];
    float fx = a0 * fmaxf(gv.x, 0.f) + a1 * fmaxf(dv.x, 0.f);
    float fy = a0 * fmaxf(gv.y, 0.f) + a1 * fmaxf(dv.y, 0.f);
    float2 w0 = *(const float2*)&lin_w[l * 2];
    float2 w1 = *(const float2*)&lin_w[128 + l * 2];
    float p0 = fx * w0.x + fy * w0.y;
    float p1 = fx * w1.x + fy * w1.y;
    for (int off = 32; off > 0; off >>= 1) {
        p0 += __shfl_down(p0, off);
        p1 += __shfl_down(p1, off);
    }
    if (l == 0) {
        float2 o;
        o.x = p0 + lin_b[0];
        o.y = p1 + lin_b[1];
        *(float2*)&outp[wid * 2] = o;
    }
}

extern "C" void kernel_launch(void* const* d_in, const int* in_sizes, int n_in,
                              void* d_out, int out_size, void* d_ws, size_t ws_size,
                              hipStream_t stream) {
    const float* x_gene    = (const float*)d_in[0];
    const float* x_disease = (const float*)d_in[1];
    const int*   edge_gg   = (const int*)d_in[2];
    const int*   edge_dg   = (const int*)d_in[3];
    const float* pg_w      = (const float*)d_in[4];
    const float* pg_b      = (const float*)d_in[5];
    const float* pd_w      = (const float*)d_in[6];
    const float* pd_b      = (const float*)d_in[7];
    const float* att_src_gg= (const float*)d_in[8];
    const float* att_dst_gg= (const float*)d_in[9];
    const float* att_src_dg= (const float*)d_in[10];
    const float* att_dst_dg= (const float*)d_in[11];
    const float* k_lin_w   = (const float*)d_in[12];
    const float* k_lin_b   = (const float*)d_in[13];
    const float* q         = (const float*)d_in[14];
    const float* lin_w     = (const float*)d_in[15];
    const float* lin_b     = (const float*)d_in[16];
    float* out = (float*)d_out;
    float* ws  = (float*)d_ws;

    float* out_gg = ws + OFF_OUT_GG;
    float* out_dg = ws + OFF_OUT_DG;
    unsigned int* colPacked = (unsigned int*)(ws + OFF_OUT_GG);  // overlay (dead until gat_gather)
    float* xg     = ws + OFF_XG;
    float* xd     = ws + OFF_XD;
    float* a_src_gg = ws + OFF_ASG;
    float* a_dst_gg = ws + OFF_ADG;
    float* a_dst_dg = ws + OFF_ADD;
    float* a_src_dg = ws + OFF_ASD;
    float* kpart  = ws + OFF_KPART;
    float* attn   = ws + OFF_ATTN;
    int* deg  = (int*)(ws + OFF_DEG);
    int* rp   = (int*)(ws + OFF_RP);
    int* bcur = (int*)(ws + OFF_BCUR);
    int* bsum = (int*)(ws + OFF_BSUM);
    int* col  = (int*)(ws + OFF_COL);

    const int* gg_src = edge_gg;
    const int* gg_dst = edge_gg + EGG;
    const int* dg_src = edge_dg;
    const int* dg_dst = edge_dg + EDG;

    // 1. zero kpart + degree arrays
    hipLaunchKernelGGL(init_zero_k, dim3((ZERO_CNT + 255) / 256), dim3(256), 0, stream,
                       ws + ZERO_BASE, ZERO_CNT);
    // 2. projections with fused att-logit epilogue
    hipLaunchKernelGGL(proj_gemm_fused, dim3(512), dim3(256), 0, stream,
                       x_gene, pg_w, pg_b, xg, NG, 3,
                       att_src_gg, att_dst_gg, att_dst_dg, a_src_gg, a_dst_gg, a_dst_dg);
    hipLaunchKernelGGL(proj_gemm_fused, dim3(512), dim3(256), 0, stream,
                       x_disease, pd_w, pd_b, xd, ND, 1,
                       att_src_dg, (const float*)nullptr, (const float*)nullptr,
                       a_src_dg, (float*)nullptr, (float*)nullptr);
    // 3. CSR row pointers
    hipLaunchKernelGGL(count_all, dim3((EALL + 255) / 256), dim3(256), 0, stream,
                       gg_dst, dg_dst, deg);
    hipLaunchKernelGGL(scan1, dim3((NALL + 1023) / 1024), dim3(256), 0, stream, deg, rp, bsum, NALL);
    hipLaunchKernelGGL(scan2, dim3(1), dim3(256), 0, stream, bsum, (NALL + 1023) / 1024);
    hipLaunchKernelGGL(scan3, dim3((NALL + 255) / 256), dim3(256), 0, stream, rp, bsum, bcur, NALL, EALL);
    // 4. two-level bucket sort into CSR col
    hipLaunchKernelGGL(bucket_scatter, dim3((EALL + S1_CH - 1) / S1_CH), dim3(256), 0, stream,
                       gg_src, gg_dst, dg_src, dg_dst, bcur, colPacked);
    hipLaunchKernelGGL(bucket_sort, dim3(NBUK), dim3(256), 0, stream, colPacked, rp, col);
    // 5. fused gathers (out_gg overwrites colPacked overlay — colPacked is dead by now)
    hipLaunchKernelGGL(gat_gather, dim3((NG + 3) / 4), dim3(256), 0, stream,
                       rp, col, a_src_gg, a_dst_gg, xg, out_gg, NG);
    hipLaunchKernelGGL(gat_gather, dim3((NG + 3) / 4), dim3(256), 0, stream,
                       rp + NG, col, a_src_dg, a_dst_dg, xd, out_dg, NG);
    // 6. semantic attention
    hipLaunchKernelGGL(kmean_gemm2, dim3(512), dim3(256), 0, stream,
                       out_gg, out_dg, k_lin_w, k_lin_b, kpart);
    hipLaunchKernelGGL(score_attn, dim3(1), dim3(128), 0, stream, kpart, q, attn);
    // 7. fused combine + final linear
    hipLaunchKernelGGL(final_lin, dim3((NG + 3) / 4), dim3(256), 0, stream,
                       out_gg, out_dg, attn, lin_w, lin_b, out);
}